// Round 4
// baseline (373.150 us; speedup 1.0000x reference)
//
#include <hip/hip_runtime.h>

#define N 6144
#define E 196608
#define EN (E + N)      // 202752
#define LGAT 10

typedef unsigned int u32;

// order-preserving float<->uint for atomicMax/Min on floats (incl. negatives)
__device__ __forceinline__ u32 f2key(float f) {
    u32 u = __float_as_uint(f);
    return (u & 0x80000000u) ? ~u : (u | 0x80000000u);
}
__device__ __forceinline__ float key2f(u32 k) {
    u32 u = (k & 0x80000000u) ? (k & 0x7FFFFFFFu) : ~k;
    return __uint_as_float(u);
}

struct P {
    // fp32 inputs
    const float *x, *mask, *gat_W, *gat_asrc, *gat_adst, *gat_b;
    const float *in_w, *in_b, *out_w, *out_b;
    const float *Wq, *bq, *Wk, *bk, *Wv, *bv, *Wsk, *bsk;
    const float *W1, *b1, *W2, *b2, *W3, *b3, *cW, *cb;
    const int *src, *dst;
    // fp32 workspace
    float *xp, *ssrc, *sdst, *qkv, *qkv2, *h2, *h3, *part;
    float *a1pre, *a2buf, *sumres;
    u32 *deg, *offs, *cursor, *kmaxk, *kmink;
    int *ssorted;
    float *out;
};

// ---- init: zero degree histogram -----------------------------------------
__global__ void k_init(P p) {
    int t = blockIdx.x * 256 + threadIdx.x;
    if (t < N) p.deg[t] = 0u;
}

// ---- CSR build pass 1: histogram of dst ----------------------------------
__global__ void k_hist(P p) {
    int e = blockIdx.x * 256 + threadIdx.x;
    if (e >= EN) return;
    int d = (e < E) ? p.dst[e] : (e - E);
    atomicAdd(&p.deg[d], 1u);
}

// ---- CSR build pass 2: exclusive scan (single block) + tiny inits --------
__global__ void k_scan(P p) {
    __shared__ u32 part[256];
    int t = threadIdx.x;
    if (t < 3) p.kmaxk[t] = 0u;
    else if (t < 6) p.kmink[t - 3] = 0xFFFFFFFFu;
    else if (t < 22) p.a1pre[t - 6] = 0.f;
    else if (t == 22) p.sumres[0] = 0.f;
    u32 loc[24];
    u32 sum = 0;
    #pragma unroll
    for (int i = 0; i < 24; ++i) { loc[i] = sum; sum += p.deg[t * 24 + i]; }
    part[t] = sum;
    __syncthreads();
    for (int o = 1; o < 256; o <<= 1) {
        u32 v = (t >= o) ? part[t - o] : 0u;
        __syncthreads();
        part[t] += v;
        __syncthreads();
    }
    u32 base = (t == 0) ? 0u : part[t - 1];
    #pragma unroll
    for (int i = 0; i < 24; ++i) {
        u32 off = base + loc[i];
        p.offs[t * 24 + i] = off;
        p.cursor[t * 24 + i] = off;
    }
    if (t == 255) p.offs[N] = part[255];
}

// ---- CSR build pass 3: scatter src ids into dst-sorted order -------------
__global__ void k_scatter(P p) {
    int e = blockIdx.x * 256 + threadIdx.x;
    if (e >= EN) return;
    int s = (e < E) ? p.src[e] : (e - E);
    int d = (e < E) ? p.dst[e] : (e - E);
    u32 pos = atomicAdd(&p.cursor[d], 1u);
    p.ssorted[pos] = s;
}

// ---- layer-0 node transform: x -> xp, ssrc, sdst -------------------------
__global__ void k_node0(P p) {
    int n = blockIdx.x * 256 + threadIdx.x;
    float h0 = p.x[n * 3 + 0], h1 = p.x[n * 3 + 1], h2 = p.x[n * 3 + 2];
    const float* W = p.gat_W;
    float xp0 = h0 * W[0] + h1 * W[3] + h2 * W[6];
    float xp1 = h0 * W[1] + h1 * W[4] + h2 * W[7];
    float xp2 = h0 * W[2] + h1 * W[5] + h2 * W[8];
    p.xp[n * 3 + 0] = xp0; p.xp[n * 3 + 1] = xp1; p.xp[n * 3 + 2] = xp2;
    p.ssrc[n] = xp0 * p.gat_asrc[0] + xp1 * p.gat_asrc[1] + xp2 * p.gat_asrc[2];
    p.sdst[n] = xp0 * p.gat_adst[0] + xp1 * p.gat_adst[1] + xp2 * p.gat_adst[2];
}

// ---- GAT edge kernel: 16 lanes/dst, single-pass online softmax -----------
// epilogue (lane 0): l<9 -> compute NEXT layer's xp/ssrc/sdst directly;
//                    l==9 -> compute qkv row + k min/max atomics.
__global__ void k_gat_edge(P p, int l) {
    int gid = blockIdx.x * 256 + threadIdx.x;
    int d = gid >> 4;
    int lane = gid & 15;
    u32 beg = p.offs[d], end = p.offs[d + 1];
    float sd = p.sdst[d];
    float m = -1e30f, sz = 0.f, s0 = 0.f, s1 = 0.f, s2 = 0.f;
    for (u32 i = beg + lane; i < end; i += 16) {
        int s = p.ssorted[i];
        float v = p.ssrc[s] + sd;
        v = (v >= 0.f) ? v : 0.2f * v;
        float mn = fmaxf(m, v);
        float sc = __expf(m - mn);
        float w = __expf(v - mn);
        sz = sz * sc + w;
        s0 = s0 * sc + w * p.xp[s * 3 + 0];
        s1 = s1 * sc + w * p.xp[s * 3 + 1];
        s2 = s2 * sc + w * p.xp[s * 3 + 2];
        m = mn;
    }
    #pragma unroll
    for (int o = 1; o < 16; o <<= 1) {
        float m2 = __shfl_xor(m, o);
        float z2 = __shfl_xor(sz, o);
        float t0 = __shfl_xor(s0, o);
        float t1 = __shfl_xor(s1, o);
        float t2 = __shfl_xor(s2, o);
        float mn = fmaxf(m, m2);
        float a = __expf(m - mn), b = __expf(m2 - mn);
        sz = sz * a + z2 * b;
        s0 = s0 * a + t0 * b;
        s1 = s1 * a + t1 * b;
        s2 = s2 * a + t2 * b;
        m = mn;
    }
    if (lane == 0) {
        float z = sz + 1e-16f;
        float o0 = s0 / z + p.gat_b[l * 3 + 0];
        float o1 = s1 / z + p.gat_b[l * 3 + 1];
        float o2 = s2 / z + p.gat_b[l * 3 + 2];
        if (l < LGAT - 1) {
            o0 = fmaxf(o0, 0.f); o1 = fmaxf(o1, 0.f); o2 = fmaxf(o2, 0.f);
            const float* W = p.gat_W + (l + 1) * 9;
            float xp0 = o0 * W[0] + o1 * W[3] + o2 * W[6];
            float xp1 = o0 * W[1] + o1 * W[4] + o2 * W[7];
            float xp2 = o0 * W[2] + o1 * W[5] + o2 * W[8];
            p.xp[d * 3 + 0] = xp0; p.xp[d * 3 + 1] = xp1; p.xp[d * 3 + 2] = xp2;
            const float* as = p.gat_asrc + (l + 1) * 3;
            const float* ad = p.gat_adst + (l + 1) * 3;
            p.ssrc[d] = xp0 * as[0] + xp1 * as[1] + xp2 * as[2];
            p.sdst[d] = xp0 * ad[0] + xp1 * ad[1] + xp2 * ad[2];
        } else {
            float kk[3];
            #pragma unroll
            for (int j = 0; j < 9; ++j) {
                float v = o0 * p.in_w[j * 3 + 0] + o1 * p.in_w[j * 3 + 1] +
                          o2 * p.in_w[j * 3 + 2] + p.in_b[j];
                p.qkv[d * 9 + j] = v;
                if (j >= 3 && j < 6) kk[j - 3] = v;
            }
            #pragma unroll
            for (int hh = 0; hh < 3; ++hh) {
                atomicMax(&p.kmaxk[hh], f2key(kk[hh]));
                atomicMin(&p.kmink[hh], f2key(kk[hh]));
            }
        }
    }
}

// ---- MHA: rank-1 attention, chunked over m; partials via plain stores ----
#define MCH 384   // 6144/16
__global__ void k_att_partial(P p) {
    __shared__ float kv[MCH * 6];
    int tid = threadIdx.x;
    int chunk = blockIdx.y;
    int mbase = chunk * MCH;
    for (int i = tid; i < MCH * 6; i += 256) {
        int mm = i / 6, r = i - mm * 6;       // r 0..2 -> k[h], 3..5 -> v[h]
        kv[i] = p.qkv[(mbase + mm) * 9 + 3 + r];
    }
    __syncthreads();
    int n = blockIdx.x * 256 + tid;
    float q0 = p.qkv[n * 9 + 0], q1 = p.qkv[n * 9 + 1], q2 = p.qkv[n * 9 + 2];
    float kmx0 = key2f(p.kmaxk[0]), kmx1 = key2f(p.kmaxk[1]), kmx2 = key2f(p.kmaxk[2]);
    float kmn0 = key2f(p.kmink[0]), kmn1 = key2f(p.kmink[1]), kmn2 = key2f(p.kmink[2]);
    // exact row max of q*k over ALL m: q>=0 -> q*kmax else q*kmin
    float M0 = (q0 >= 0.f) ? q0 * kmx0 : q0 * kmn0;
    float M1 = (q1 >= 0.f) ? q1 * kmx1 : q1 * kmn1;
    float M2 = (q2 >= 0.f) ? q2 * kmx2 : q2 * kmn2;
    float num0 = 0, den0 = 0, num1 = 0, den1 = 0, num2 = 0, den2 = 0;
    for (int mm = 0; mm < MCH; ++mm) {
        float k0 = kv[mm * 6 + 0], k1 = kv[mm * 6 + 1], k2 = kv[mm * 6 + 2];
        float v0 = kv[mm * 6 + 3], v1 = kv[mm * 6 + 4], v2 = kv[mm * 6 + 5];
        float t0 = __expf(q0 * k0 - M0); den0 += t0; num0 += t0 * v0;
        float t1 = __expf(q1 * k1 - M1); den1 += t1; num1 += t1 * v1;
        float t2 = __expf(q2 * k2 - M2); den2 += t2; num2 += t2 * v2;
    }
    float* pp = p.part + ((size_t)chunk * N + n) * 6;
    pp[0] = num0; pp[1] = den0; pp[2] = num1; pp[3] = den1; pp[4] = num2; pp[5] = den2;
}

// ---- MHA reduce + out-proj + TC q2/k2/v2 ---------------------------------
__global__ void k_att_reduce(P p) {
    int n = blockIdx.x * 256 + threadIdx.x;
    float num[3] = {0.f, 0.f, 0.f}, den[3] = {0.f, 0.f, 0.f};
    for (int c = 0; c < 16; ++c) {
        const float* pp = p.part + ((size_t)c * N + n) * 6;
        #pragma unroll
        for (int hh = 0; hh < 3; ++hh) {
            num[hh] += pp[hh * 2];
            den[hh] += pp[hh * 2 + 1];
        }
    }
    float o[3];
    #pragma unroll
    for (int hh = 0; hh < 3; ++hh) o[hh] = num[hh] / den[hh];
    float h2v[3];
    #pragma unroll
    for (int c = 0; c < 3; ++c) {
        h2v[c] = p.out_b[c] + o[0] * p.out_w[c * 3 + 0] +
                 o[1] * p.out_w[c * 3 + 1] + o[2] * p.out_w[c * 3 + 2];
        p.h2[n * 3 + c] = h2v[c];
    }
    #pragma unroll
    for (int c = 0; c < 3; ++c) {
        float q2 = p.bq[c] + h2v[0] * p.Wq[c] + h2v[1] * p.Wq[3 + c] + h2v[2] * p.Wq[6 + c];
        float k2 = p.bk[c] + h2v[0] * p.Wk[c] + h2v[1] * p.Wk[3 + c] + h2v[2] * p.Wk[6 + c];
        float v2 = p.bv[c] + h2v[0] * p.Wv[c] + h2v[1] * p.Wv[3 + c] + h2v[2] * p.Wv[6 + c];
        p.qkv2[n * 9 + c] = q2;
        p.qkv2[n * 9 + 3 + c] = k2;
        p.qkv2[n * 9 + 6 + c] = v2;
    }
}

// ---- TC fused edge kernel: 16 lanes/dst, online softmax, skip fused ------
__global__ void k_tc_edge(P p) {
    int gid = blockIdx.x * 256 + threadIdx.x;
    int d = gid >> 4;
    int lane = gid & 15;
    u32 beg = p.offs[d], end = p.offs[d + 1];
    float q0 = p.qkv2[d * 9 + 0], q1 = p.qkv2[d * 9 + 1], q2 = p.qkv2[d * 9 + 2];
    const float RS3 = 0.57735026919f;
    float m = -1e30f, sz = 0.f, s0 = 0.f, s1 = 0.f, s2 = 0.f;
    for (u32 i = beg + lane; i < end; i += 16) {
        int s = p.ssorted[i];
        float lg = (q0 * p.qkv2[s * 9 + 3] + q1 * p.qkv2[s * 9 + 4] +
                    q2 * p.qkv2[s * 9 + 5]) * RS3;
        float mn = fmaxf(m, lg);
        float sc = __expf(m - mn);
        float w = __expf(lg - mn);
        sz = sz * sc + w;
        s0 = s0 * sc + w * p.qkv2[s * 9 + 6];
        s1 = s1 * sc + w * p.qkv2[s * 9 + 7];
        s2 = s2 * sc + w * p.qkv2[s * 9 + 8];
        m = mn;
    }
    #pragma unroll
    for (int o = 1; o < 16; o <<= 1) {
        float m2 = __shfl_xor(m, o);
        float z2 = __shfl_xor(sz, o);
        float t0 = __shfl_xor(s0, o);
        float t1 = __shfl_xor(s1, o);
        float t2 = __shfl_xor(s2, o);
        float mn = fmaxf(m, m2);
        float a = __expf(m - mn), b = __expf(m2 - mn);
        sz = sz * a + z2 * b;
        s0 = s0 * a + t0 * b;
        s1 = s1 * a + t1 * b;
        s2 = s2 * a + t2 * b;
        m = mn;
    }
    if (lane == 0) {
        float z = sz + 1e-16f;
        float h0 = p.h2[d * 3 + 0], h1 = p.h2[d * 3 + 1], h2 = p.h2[d * 3 + 2];
        float agg[3] = {s0 / z, s1 / z, s2 / z};
        #pragma unroll
        for (int c = 0; c < 3; ++c) {
            p.h3[d * 3 + c] = agg[c] + p.bsk[c] +
                h0 * p.Wsk[c] + h1 * p.Wsk[3 + c] + h2 * p.Wsk[6 + c];
        }
    }
}

// ---- MLP stage 1: flat(18432) @ W1(18432x16) -> a1pre[16] ----------------
__global__ void k_mlp1(P p) {
    int g = blockIdx.x * 256 + threadIdx.x;   // 6144 threads
    float acc[16];
    #pragma unroll
    for (int j = 0; j < 16; ++j) acc[j] = 0.f;
    for (int i = g; i < 3 * N; i += 6144) {
        float f = p.h3[i];
        const float* w = p.W1 + (size_t)i * 16;
        #pragma unroll
        for (int j = 0; j < 16; ++j) acc[j] += f * w[j];
    }
    #pragma unroll
    for (int o = 32; o; o >>= 1)
        #pragma unroll
        for (int j = 0; j < 16; ++j) acc[j] += __shfl_xor(acc[j], o);
    if ((threadIdx.x & 63) == 0)
        #pragma unroll
        for (int j = 0; j < 16; ++j) atomicAdd(&p.a1pre[j], acc[j]);
}

// ---- MLP stage 2: a1 -> a2 (tiny) ----------------------------------------
__global__ void k_mlp2(P p) {
    __shared__ float a1[16];
    int t = threadIdx.x;
    if (t < 16) a1[t] = fmaxf(p.a1pre[t] + p.b1[t], 0.f);
    __syncthreads();
    if (t < 32) {
        float acc = p.b2[t];
        #pragma unroll
        for (int i = 0; i < 16; ++i) acc += a1[i] * p.W2[i * 32 + t];
        p.a2buf[t] = fmaxf(acc, 0.f);
    }
}

// ---- MLP stage 3: results = a2 @ W3 + b3; out, mean ----------------------
__global__ void k_mlp3(P p) {
    __shared__ float a2[32];
    if (threadIdx.x < 32) a2[threadIdx.x] = p.a2buf[threadIdx.x];
    __syncthreads();
    int n = blockIdx.x * 256 + threadIdx.x;
    float acc = p.b3[n];
    #pragma unroll
    for (int j = 0; j < 32; ++j) acc += a2[j] * p.W3[(size_t)j * N + n];
    p.out[n] = acc * p.mask[n];
    float s = acc;
    #pragma unroll
    for (int o = 32; o; o >>= 1) s += __shfl_xor(s, o);
    if ((threadIdx.x & 63) == 0) atomicAdd(p.sumres, s);
}

// ---- value ---------------------------------------------------------------
__global__ void k_value(P p) {
    p.out[N] = p.cW[0] * (p.sumres[0] / (float)N) + p.cb[0];
}

extern "C" void kernel_launch(void* const* d_in, const int* in_sizes, int n_in,
                              void* d_out, int out_size, void* d_ws, size_t ws_size,
                              hipStream_t stream) {
    P p;
    p.x      = (const float*)d_in[0];
    p.mask   = (const float*)d_in[1];
    const int* ei = (const int*)d_in[2];
    p.src = ei; p.dst = ei + E;
    p.gat_W  = (const float*)d_in[3];
    p.gat_asrc = (const float*)d_in[4];
    p.gat_adst = (const float*)d_in[5];
    p.gat_b  = (const float*)d_in[6];
    p.in_w   = (const float*)d_in[7];
    p.in_b   = (const float*)d_in[8];
    p.out_w  = (const float*)d_in[9];
    p.out_b  = (const float*)d_in[10];
    p.Wq = (const float*)d_in[11]; p.bq = (const float*)d_in[12];
    p.Wk = (const float*)d_in[13]; p.bk = (const float*)d_in[14];
    p.Wv = (const float*)d_in[15]; p.bv = (const float*)d_in[16];
    p.Wsk = (const float*)d_in[17]; p.bsk = (const float*)d_in[18];
    p.W1 = (const float*)d_in[19]; p.b1 = (const float*)d_in[20];
    p.W2 = (const float*)d_in[21]; p.b2 = (const float*)d_in[22];
    p.W3 = (const float*)d_in[23]; p.b3 = (const float*)d_in[24];
    p.cW = (const float*)d_in[25]; p.cb = (const float*)d_in[26];

    float* ws = (float*)d_ws;
    p.xp      = ws + 0;          // 18432
    p.ssrc    = ws + 18432;      // 6144
    p.sdst    = ws + 24576;      // 6144
    p.qkv     = ws + 30720;      // 55296
    p.qkv2    = ws + 86016;      // 55296
    p.h2      = ws + 141312;     // 18432
    p.h3      = ws + 159744;     // 18432
    p.part    = ws + 178176;     // 589824 (16*6144*6)
    p.deg     = (u32*)(ws + 768000);   // 6144
    p.offs    = (u32*)(ws + 774144);   // 6145
    p.cursor  = (u32*)(ws + 780289);   // 6144
    p.ssorted = (int*)(ws + 786433);   // 202752
    p.a1pre   = ws + 989185;     // 16
    p.a2buf   = ws + 989201;     // 32
    p.sumres  = ws + 989233;     // 1
    p.kmaxk   = (u32*)(ws + 989234);   // 3
    p.kmink   = (u32*)(ws + 989237);   // 3
    p.out     = (float*)d_out;

    // CSR build (once per launch)
    k_init<<<24, 256, 0, stream>>>(p);
    k_hist<<<792, 256, 0, stream>>>(p);
    k_scan<<<1, 256, 0, stream>>>(p);
    k_scatter<<<792, 256, 0, stream>>>(p);
    // GAT stack (node transforms fused into edge epilogues)
    k_node0<<<24, 256, 0, stream>>>(p);
    for (int l = 0; l < LGAT; ++l)
        k_gat_edge<<<384, 256, 0, stream>>>(p, l);
    // MHA
    k_att_partial<<<dim3(24, 16), 256, 0, stream>>>(p);
    k_att_reduce<<<24, 256, 0, stream>>>(p);
    // TC
    k_tc_edge<<<384, 256, 0, stream>>>(p);
    // MLP
    k_mlp1<<<24, 256, 0, stream>>>(p);
    k_mlp2<<<1, 64, 0, stream>>>(p);
    k_mlp3<<<24, 256, 0, stream>>>(p);
    k_value<<<1, 1, 0, stream>>>(p);
}

// Round 5
// 250.734 us; speedup vs baseline: 1.4882x; 1.4882x over previous
//
#include <hip/hip_runtime.h>

#define N 6144
#define E 196608
#define EN (E + N)      // 202752
#define LGAT 10

typedef unsigned int u32;

// order-preserving float<->uint for atomicMax/Min on floats (incl. negatives)
__device__ __forceinline__ u32 f2key(float f) {
    u32 u = __float_as_uint(f);
    return (u & 0x80000000u) ? ~u : (u | 0x80000000u);
}
__device__ __forceinline__ float key2f(u32 k) {
    u32 u = (k & 0x80000000u) ? (k & 0x7FFFFFFFu) : ~k;
    return __uint_as_float(u);
}

struct P {
    // fp32 inputs
    const float *x, *mask, *gat_W, *gat_asrc, *gat_adst, *gat_b;
    const float *in_w, *in_b, *out_w, *out_b;
    const float *Wq, *bq, *Wk, *bk, *Wv, *bv, *Wsk, *bsk;
    const float *W1, *b1, *W2, *b2, *W3, *b3, *cW, *cb;
    const int *src, *dst;
    // fp32 workspace
    float4 *nodeA, *nodeB;          // per-node {xp0,xp1,xp2,ssrc}
    float *sdstA, *sdstB;
    float *qkv, *q2, *h2, *h3, *part;
    float4 *kv2;                    // per-node 2x float4 {k0,k1,k2,v0},{v1,v2,_,_}
    float *a1pre, *a2buf, *sumres;
    u32 *deg, *offs, *cursor, *kmaxk, *kmink;
    int *ssorted;
    float *out;
};

// ---- init: zero degree histogram -----------------------------------------
__global__ void k_init(P p) {
    int t = blockIdx.x * 256 + threadIdx.x;
    if (t < N) p.deg[t] = 0u;
}

// ---- CSR build pass 1: histogram of dst ----------------------------------
__global__ void k_hist(P p) {
    int e = blockIdx.x * 256 + threadIdx.x;
    if (e >= EN) return;
    int d = (e < E) ? p.dst[e] : (e - E);
    atomicAdd(&p.deg[d], 1u);
}

// ---- CSR build pass 2: exclusive scan (single block) + tiny inits --------
__global__ void k_scan(P p) {
    __shared__ u32 part[256];
    int t = threadIdx.x;
    if (t < 3) p.kmaxk[t] = 0u;
    else if (t < 6) p.kmink[t - 3] = 0xFFFFFFFFu;
    else if (t < 22) p.a1pre[t - 6] = 0.f;
    else if (t == 22) p.sumres[0] = 0.f;
    u32 loc[24];
    u32 sum = 0;
    #pragma unroll
    for (int i = 0; i < 24; ++i) { loc[i] = sum; sum += p.deg[t * 24 + i]; }
    part[t] = sum;
    __syncthreads();
    for (int o = 1; o < 256; o <<= 1) {
        u32 v = (t >= o) ? part[t - o] : 0u;
        __syncthreads();
        part[t] += v;
        __syncthreads();
    }
    u32 base = (t == 0) ? 0u : part[t - 1];
    #pragma unroll
    for (int i = 0; i < 24; ++i) {
        u32 off = base + loc[i];
        p.offs[t * 24 + i] = off;
        p.cursor[t * 24 + i] = off;
    }
    if (t == 255) p.offs[N] = part[255];
}

// ---- CSR build pass 3: scatter src ids into dst-sorted order -------------
__global__ void k_scatter(P p) {
    int e = blockIdx.x * 256 + threadIdx.x;
    if (e >= EN) return;
    int s = (e < E) ? p.src[e] : (e - E);
    int d = (e < E) ? p.dst[e] : (e - E);
    u32 pos = atomicAdd(&p.cursor[d], 1u);
    p.ssorted[pos] = s;
}

// ---- layer-0 node transform: x -> nodeA records ---------------------------
__global__ void k_node0(P p) {
    int n = blockIdx.x * 256 + threadIdx.x;
    float h0 = p.x[n * 3 + 0], h1 = p.x[n * 3 + 1], h2 = p.x[n * 3 + 2];
    const float* W = p.gat_W;
    float xp0 = h0 * W[0] + h1 * W[3] + h2 * W[6];
    float xp1 = h0 * W[1] + h1 * W[4] + h2 * W[7];
    float xp2 = h0 * W[2] + h1 * W[5] + h2 * W[8];
    float ss = xp0 * p.gat_asrc[0] + xp1 * p.gat_asrc[1] + xp2 * p.gat_asrc[2];
    p.nodeA[n] = make_float4(xp0, xp1, xp2, ss);
    p.sdstA[n] = xp0 * p.gat_adst[0] + xp1 * p.gat_adst[1] + xp2 * p.gat_adst[2];
}

// ---- GAT edge kernel: 32 lanes/dst, two-pass softmax, float4 gathers -----
// Reads nin/sdin (layer l records), writes nout/sdout (layer l+1 records)
// via lane-0 epilogue; l==9 writes the qkv rows instead. No same-buffer race.
__global__ void k_gat_edge(P p, const float4* __restrict__ nin,
                           const float* __restrict__ sdin,
                           float4* __restrict__ nout, float* __restrict__ sdout,
                           int l) {
    int gid = blockIdx.x * 256 + threadIdx.x;
    int d = gid >> 5;
    int lane = gid & 31;
    u32 beg = p.offs[d], end = p.offs[d + 1];
    float sd = sdin[d];
    // pass 1: max
    float mx = -1e30f;
    for (u32 i = beg + lane; i < end; i += 32) {
        float4 r = nin[p.ssorted[i]];
        float v = r.w + sd;
        v = (v >= 0.f) ? v : 0.2f * v;
        mx = fmaxf(mx, v);
    }
    #pragma unroll
    for (int o = 1; o < 32; o <<= 1) mx = fmaxf(mx, __shfl_xor(mx, o));
    // pass 2: exp-sum + weighted aggregation (reloads are L1-hot)
    float sz = 0.f, s0 = 0.f, s1 = 0.f, s2 = 0.f;
    for (u32 i = beg + lane; i < end; i += 32) {
        float4 r = nin[p.ssorted[i]];
        float v = r.w + sd;
        v = (v >= 0.f) ? v : 0.2f * v;
        float w = __expf(v - mx);
        sz += w;
        s0 += w * r.x; s1 += w * r.y; s2 += w * r.z;
    }
    #pragma unroll
    for (int o = 1; o < 32; o <<= 1) {
        sz += __shfl_xor(sz, o);
        s0 += __shfl_xor(s0, o);
        s1 += __shfl_xor(s1, o);
        s2 += __shfl_xor(s2, o);
    }
    if (lane == 0) {
        float z = sz + 1e-16f;
        float o0 = s0 / z + p.gat_b[l * 3 + 0];
        float o1 = s1 / z + p.gat_b[l * 3 + 1];
        float o2 = s2 / z + p.gat_b[l * 3 + 2];
        if (l < LGAT - 1) {
            o0 = fmaxf(o0, 0.f); o1 = fmaxf(o1, 0.f); o2 = fmaxf(o2, 0.f);
            const float* W = p.gat_W + (l + 1) * 9;
            float xp0 = o0 * W[0] + o1 * W[3] + o2 * W[6];
            float xp1 = o0 * W[1] + o1 * W[4] + o2 * W[7];
            float xp2 = o0 * W[2] + o1 * W[5] + o2 * W[8];
            const float* as = p.gat_asrc + (l + 1) * 3;
            const float* ad = p.gat_adst + (l + 1) * 3;
            float ss = xp0 * as[0] + xp1 * as[1] + xp2 * as[2];
            nout[d] = make_float4(xp0, xp1, xp2, ss);
            sdout[d] = xp0 * ad[0] + xp1 * ad[1] + xp2 * ad[2];
        } else {
            // final layer (no relu): project to qkv
            #pragma unroll
            for (int j = 0; j < 9; ++j) {
                float v = o0 * p.in_w[j * 3 + 0] + o1 * p.in_w[j * 3 + 1] +
                          o2 * p.in_w[j * 3 + 2] + p.in_b[j];
                p.qkv[d * 9 + j] = v;
            }
        }
    }
}

// ---- global k min/max per head (wave pre-reduced -> 576 atomics total) ---
__global__ void k_kminmax(P p) {
    int n = blockIdx.x * 256 + threadIdx.x;
    float kk[3];
    #pragma unroll
    for (int hh = 0; hh < 3; ++hh) kk[hh] = p.qkv[n * 9 + 3 + hh];
    #pragma unroll
    for (int hh = 0; hh < 3; ++hh) {
        float mx = kk[hh], mn = kk[hh];
        #pragma unroll
        for (int o = 32; o; o >>= 1) {
            mx = fmaxf(mx, __shfl_xor(mx, o));
            mn = fminf(mn, __shfl_xor(mn, o));
        }
        if ((threadIdx.x & 63) == 0) {
            atomicMax(&p.kmaxk[hh], f2key(mx));
            atomicMin(&p.kmink[hh], f2key(mn));
        }
    }
}

// ---- MHA: rank-1 attention, 32 chunks, planar partial stores -------------
#define MCH 192   // 6144/32
__global__ void k_att_partial(P p) {
    __shared__ float kv[MCH * 6];
    int tid = threadIdx.x;
    int chunk = blockIdx.y;
    int mbase = chunk * MCH;
    for (int i = tid; i < MCH * 6; i += 256) {
        int mm = i / 6, r = i - mm * 6;       // r 0..2 -> k[h], 3..5 -> v[h]
        kv[i] = p.qkv[(mbase + mm) * 9 + 3 + r];
    }
    __syncthreads();
    int n = blockIdx.x * 256 + tid;
    float q0 = p.qkv[n * 9 + 0], q1 = p.qkv[n * 9 + 1], q2 = p.qkv[n * 9 + 2];
    float kmx0 = key2f(p.kmaxk[0]), kmx1 = key2f(p.kmaxk[1]), kmx2 = key2f(p.kmaxk[2]);
    float kmn0 = key2f(p.kmink[0]), kmn1 = key2f(p.kmink[1]), kmn2 = key2f(p.kmink[2]);
    // exact row max of q*k over ALL m: q>=0 -> q*kmax else q*kmin
    float M0 = (q0 >= 0.f) ? q0 * kmx0 : q0 * kmn0;
    float M1 = (q1 >= 0.f) ? q1 * kmx1 : q1 * kmn1;
    float M2 = (q2 >= 0.f) ? q2 * kmx2 : q2 * kmn2;
    float num0 = 0, den0 = 0, num1 = 0, den1 = 0, num2 = 0, den2 = 0;
    for (int mm = 0; mm < MCH; ++mm) {
        float k0 = kv[mm * 6 + 0], k1 = kv[mm * 6 + 1], k2 = kv[mm * 6 + 2];
        float v0 = kv[mm * 6 + 3], v1 = kv[mm * 6 + 4], v2 = kv[mm * 6 + 5];
        float t0 = __expf(q0 * k0 - M0); den0 += t0; num0 += t0 * v0;
        float t1 = __expf(q1 * k1 - M1); den1 += t1; num1 += t1 * v1;
        float t2 = __expf(q2 * k2 - M2); den2 += t2; num2 += t2 * v2;
    }
    // planar layout part[(chunk*6 + r)*N + n] -> coalesced stores
    float* pp = p.part + (size_t)chunk * 6 * N + n;
    pp[0] = num0; pp[N] = den0; pp[2 * N] = num1;
    pp[3 * N] = den1; pp[4 * N] = num2; pp[5 * N] = den2;
}

// ---- MHA reduce + out-proj + TC q2/kv2 records ---------------------------
__global__ void k_att_reduce(P p) {
    int n = blockIdx.x * 256 + threadIdx.x;
    float num[3] = {0.f, 0.f, 0.f}, den[3] = {0.f, 0.f, 0.f};
    for (int c = 0; c < 32; ++c) {
        const float* pp = p.part + (size_t)c * 6 * N + n;
        #pragma unroll
        for (int hh = 0; hh < 3; ++hh) {
            num[hh] += pp[hh * 2 * N];
            den[hh] += pp[(hh * 2 + 1) * N];
        }
    }
    float o[3];
    #pragma unroll
    for (int hh = 0; hh < 3; ++hh) o[hh] = num[hh] / den[hh];
    float h2v[3];
    #pragma unroll
    for (int c = 0; c < 3; ++c) {
        h2v[c] = p.out_b[c] + o[0] * p.out_w[c * 3 + 0] +
                 o[1] * p.out_w[c * 3 + 1] + o[2] * p.out_w[c * 3 + 2];
        p.h2[n * 3 + c] = h2v[c];
    }
    float q2v[3], k2v[3], v2v[3];
    #pragma unroll
    for (int c = 0; c < 3; ++c) {
        q2v[c] = p.bq[c] + h2v[0] * p.Wq[c] + h2v[1] * p.Wq[3 + c] + h2v[2] * p.Wq[6 + c];
        k2v[c] = p.bk[c] + h2v[0] * p.Wk[c] + h2v[1] * p.Wk[3 + c] + h2v[2] * p.Wk[6 + c];
        v2v[c] = p.bv[c] + h2v[0] * p.Wv[c] + h2v[1] * p.Wv[3 + c] + h2v[2] * p.Wv[6 + c];
        p.q2[n * 3 + c] = q2v[c];
    }
    p.kv2[n * 2 + 0] = make_float4(k2v[0], k2v[1], k2v[2], v2v[0]);
    p.kv2[n * 2 + 1] = make_float4(v2v[1], v2v[2], 0.f, 0.f);
}

// ---- TC fused edge kernel: 32 lanes/dst, two-pass, float4 gathers --------
__global__ void k_tc_edge(P p) {
    int gid = blockIdx.x * 256 + threadIdx.x;
    int d = gid >> 5;
    int lane = gid & 31;
    u32 beg = p.offs[d], end = p.offs[d + 1];
    float q0 = p.q2[d * 3 + 0], q1 = p.q2[d * 3 + 1], q2 = p.q2[d * 3 + 2];
    const float RS3 = 0.57735026919f;
    float mx = -1e30f;
    for (u32 i = beg + lane; i < end; i += 32) {
        float4 ka = p.kv2[p.ssorted[i] * 2];
        float lg = (q0 * ka.x + q1 * ka.y + q2 * ka.z) * RS3;
        mx = fmaxf(mx, lg);
    }
    #pragma unroll
    for (int o = 1; o < 32; o <<= 1) mx = fmaxf(mx, __shfl_xor(mx, o));
    float sz = 0.f, s0 = 0.f, s1 = 0.f, s2 = 0.f;
    for (u32 i = beg + lane; i < end; i += 32) {
        int s = p.ssorted[i];
        float4 ka = p.kv2[s * 2];
        float4 kb = p.kv2[s * 2 + 1];
        float lg = (q0 * ka.x + q1 * ka.y + q2 * ka.z) * RS3;
        float w = __expf(lg - mx);
        sz += w;
        s0 += w * ka.w; s1 += w * kb.x; s2 += w * kb.y;
    }
    #pragma unroll
    for (int o = 1; o < 32; o <<= 1) {
        sz += __shfl_xor(sz, o);
        s0 += __shfl_xor(s0, o);
        s1 += __shfl_xor(s1, o);
        s2 += __shfl_xor(s2, o);
    }
    if (lane == 0) {
        float z = sz + 1e-16f;
        float h0 = p.h2[d * 3 + 0], h1 = p.h2[d * 3 + 1], h2 = p.h2[d * 3 + 2];
        float agg[3] = {s0 / z, s1 / z, s2 / z};
        #pragma unroll
        for (int c = 0; c < 3; ++c) {
            p.h3[d * 3 + c] = agg[c] + p.bsk[c] +
                h0 * p.Wsk[c] + h1 * p.Wsk[3 + c] + h2 * p.Wsk[6 + c];
        }
    }
}

// ---- MLP stage 1: flat(18432) @ W1(18432x16), fully coalesced ------------
// 18432 threads; thread t owns output column j=t&15, rows r = (t>>4)+k*1152.
__global__ void k_mlp1(P p) {
    __shared__ float red[64];   // 4 waves x 16
    int t = blockIdx.x * 256 + threadIdx.x;
    int j = t & 15;
    int g = t >> 4;             // 0..1151
    float acc = 0.f;
    #pragma unroll
    for (int k = 0; k < 16; ++k) {
        int r = g + k * 1152;
        acc += p.h3[r] * p.W1[r * 16 + j];
    }
    acc += __shfl_xor(acc, 16);
    acc += __shfl_xor(acc, 32);
    int tid = threadIdx.x;
    if ((tid & 63) < 16) red[(tid >> 6) * 16 + j] = acc;
    __syncthreads();
    if (tid < 16) {
        float s = red[tid] + red[16 + tid] + red[32 + tid] + red[48 + tid];
        atomicAdd(&p.a1pre[tid], s);
    }
}

// ---- MLP stage 2: a1 -> a2 (tiny) ----------------------------------------
__global__ void k_mlp2(P p) {
    __shared__ float a1[16];
    int t = threadIdx.x;
    if (t < 16) a1[t] = fmaxf(p.a1pre[t] + p.b1[t], 0.f);
    __syncthreads();
    if (t < 32) {
        float acc = p.b2[t];
        #pragma unroll
        for (int i = 0; i < 16; ++i) acc += a1[i] * p.W2[i * 32 + t];
        p.a2buf[t] = fmaxf(acc, 0.f);
    }
}

// ---- MLP stage 3: results = a2 @ W3 + b3; out, mean ----------------------
__global__ void k_mlp3(P p) {
    __shared__ float a2[32];
    if (threadIdx.x < 32) a2[threadIdx.x] = p.a2buf[threadIdx.x];
    __syncthreads();
    int n = blockIdx.x * 256 + threadIdx.x;
    float acc = p.b3[n];
    #pragma unroll
    for (int j = 0; j < 32; ++j) acc += a2[j] * p.W3[(size_t)j * N + n];
    p.out[n] = acc * p.mask[n];
    float s = acc;
    #pragma unroll
    for (int o = 32; o; o >>= 1) s += __shfl_xor(s, o);
    if ((threadIdx.x & 63) == 0) atomicAdd(p.sumres, s);
}

// ---- value ---------------------------------------------------------------
__global__ void k_value(P p) {
    p.out[N] = p.cW[0] * (p.sumres[0] / (float)N) + p.cb[0];
}

extern "C" void kernel_launch(void* const* d_in, const int* in_sizes, int n_in,
                              void* d_out, int out_size, void* d_ws, size_t ws_size,
                              hipStream_t stream) {
    P p;
    p.x      = (const float*)d_in[0];
    p.mask   = (const float*)d_in[1];
    const int* ei = (const int*)d_in[2];
    p.src = ei; p.dst = ei + E;
    p.gat_W  = (const float*)d_in[3];
    p.gat_asrc = (const float*)d_in[4];
    p.gat_adst = (const float*)d_in[5];
    p.gat_b  = (const float*)d_in[6];
    p.in_w   = (const float*)d_in[7];
    p.in_b   = (const float*)d_in[8];
    p.out_w  = (const float*)d_in[9];
    p.out_b  = (const float*)d_in[10];
    p.Wq = (const float*)d_in[11]; p.bq = (const float*)d_in[12];
    p.Wk = (const float*)d_in[13]; p.bk = (const float*)d_in[14];
    p.Wv = (const float*)d_in[15]; p.bv = (const float*)d_in[16];
    p.Wsk = (const float*)d_in[17]; p.bsk = (const float*)d_in[18];
    p.W1 = (const float*)d_in[19]; p.b1 = (const float*)d_in[20];
    p.W2 = (const float*)d_in[21]; p.b2 = (const float*)d_in[22];
    p.W3 = (const float*)d_in[23]; p.b3 = (const float*)d_in[24];
    p.cW = (const float*)d_in[25]; p.cb = (const float*)d_in[26];

    float* ws = (float*)d_ws;
    p.nodeA   = (float4*)(ws + 0);       // 24576 floats
    p.nodeB   = (float4*)(ws + 24576);   // 24576
    p.sdstA   = ws + 49152;              // 6144
    p.sdstB   = ws + 55296;              // 6144
    p.qkv     = ws + 61440;              // 55296
    p.q2      = ws + 116736;             // 18432
    p.kv2     = (float4*)(ws + 135168);  // 49152
    p.h2      = ws + 184320;             // 18432
    p.h3      = ws + 202752;             // 18432
    p.part    = ws + 221184;             // 32*6*6144 = 1179648
    p.a1pre   = ws + 1400832;            // 16
    p.a2buf   = ws + 1400848;            // 32
    p.sumres  = ws + 1400880;            // 1
    p.kmaxk   = (u32*)(ws + 1400884);    // 3
    p.kmink   = (u32*)(ws + 1400887);    // 3
    p.deg     = (u32*)(ws + 1400890);    // 6144
    p.offs    = (u32*)(ws + 1407034);    // 6145
    p.cursor  = (u32*)(ws + 1413179);    // 6144
    p.ssorted = (int*)(ws + 1419323);    // 202752
    p.out     = (float*)d_out;

    // CSR build (once per launch)
    k_init<<<24, 256, 0, stream>>>(p);
    k_hist<<<792, 256, 0, stream>>>(p);
    k_scan<<<1, 256, 0, stream>>>(p);
    k_scatter<<<792, 256, 0, stream>>>(p);
    // GAT stack: node transforms fused into edge epilogues, ping-pong buffers
    k_node0<<<24, 256, 0, stream>>>(p);
    for (int l = 0; l < LGAT; ++l) {
        const float4* nin = (l & 1) ? p.nodeB : p.nodeA;
        const float*  sdin = (l & 1) ? p.sdstB : p.sdstA;
        float4* nout = (l & 1) ? p.nodeA : p.nodeB;
        float*  sdout = (l & 1) ? p.sdstA : p.sdstB;
        k_gat_edge<<<768, 256, 0, stream>>>(p, nin, sdin, nout, sdout, l);
    }
    // MHA
    k_kminmax<<<24, 256, 0, stream>>>(p);
    k_att_partial<<<dim3(24, 32), 256, 0, stream>>>(p);
    k_att_reduce<<<24, 256, 0, stream>>>(p);
    // TC
    k_tc_edge<<<768, 256, 0, stream>>>(p);
    // MLP
    k_mlp1<<<72, 256, 0, stream>>>(p);
    k_mlp2<<<1, 64, 0, stream>>>(p);
    k_mlp3<<<24, 256, 0, stream>>>(p);
    k_value<<<1, 1, 0, stream>>>(p);
}